// Round 9
// baseline (268.496 us; speedup 1.0000x reference)
//
#include <hip/hip_runtime.h>
#include <hip/hip_bf16.h>

// WeightedLoss round 9: whole-tile LDS staging. Round 8's K=32-slice loop paid
// a vmcnt(0)+barrier drain every 16 MFMAs (24 barriers/block in loss) -> both
// gram kernels stuck ~100 us at 9% MfmaUtil. Now each phase stages a full
// 128x128 bf16 tile pair (64 KB LDS, 8 global_load_lds rounds/matrix), one
// barrier pair, then 64 MFMAs + 32 ds_read_b128 uninterrupted. 6 barriers
// per loss block instead of 24. LDS caps occupancy at 2 blocks/CU, so
// __launch_bounds__(256,2) gives a 256-reg budget (no spill). Loss parks raw
// sim as packed f16 in 32 regs across the out-gram (no HBM materialization).
// ws: [0] Ob bf16 8192x256 | [4 MB] Ln bf16 8192x128 | [6291456] sq f32
//     [6324224] pos_sums | [6356992] neg_sums | [6389760] stats u32[3]

#define B_N 8192
#define NT   64
#define TILE 128
#define NTRI 2080

typedef __attribute__((ext_vector_type(8))) short bf16x8;
typedef __attribute__((ext_vector_type(4))) float f32x4;
typedef __attribute__((ext_vector_type(2))) _Float16 f16x2;

typedef const __attribute__((address_space(1))) void g_void;
typedef __attribute__((address_space(3))) void l_void;

__device__ __forceinline__ unsigned fenc(float f) {
    unsigned u = __float_as_uint(f);
    return (u & 0x80000000u) ? ~u : (u | 0x80000000u);
}
__device__ __forceinline__ float fdec(unsigned k) {
    unsigned u = (k & 0x80000000u) ? (k ^ 0x80000000u) : ~k;
    return __uint_as_float(u);
}
__device__ __forceinline__ unsigned pack2(float a, float b) {
    f16x2 p; p[0] = (_Float16)a; p[1] = (_Float16)b;
    return *(unsigned*)&p;
}

// XCD-swizzled upper-tri decode.
__device__ __forceinline__ void tri_decode_swz(int b, int& bi, int& bj) {
    int t = (b & 7) * (NTRI / 8) + (b >> 3);
    int i = 0, rem = t;
    while (rem >= NT - i) { rem -= NT - i; i++; }
    bi = i; bj = i + rem;
}

// ---------------------------------------------------------------- prep ----
__global__ __launch_bounds__(256) void prep_kernel(
    const float* __restrict__ outputs, const float* __restrict__ labels,
    __hip_bfloat16* __restrict__ Ob, __hip_bfloat16* __restrict__ Ln,
    float* __restrict__ sq, float* __restrict__ pos_sums,
    float* __restrict__ neg_sums, unsigned* __restrict__ stats) {
    int w = threadIdx.x >> 6, lane = threadIdx.x & 63;
    int r = blockIdx.x * 4 + w;
    f32x4 v = ((const f32x4*)outputs)[r * 64 + lane];
    float s = v[0]*v[0] + v[1]*v[1] + v[2]*v[2] + v[3]*v[3];
    #pragma unroll
    for (int m = 1; m < 64; m <<= 1) s += __shfl_xor(s, m);
    if (lane == 0) { sq[r] = s; pos_sums[r] = 0.f; neg_sums[r] = 0.f; }
    __hip_bfloat16 o4[4];
    #pragma unroll
    for (int i = 0; i < 4; i++) o4[i] = __float2bfloat16(v[i]);
    *(uint2*)&Ob[(size_t)r * 256 + lane * 4] = *(uint2*)o4;

    float2 lv = ((const float2*)labels)[r * 64 + lane];
    float ls = lv.x * lv.x + lv.y * lv.y;
    #pragma unroll
    for (int m = 1; m < 64; m <<= 1) ls += __shfl_xor(ls, m);
    float nrm = sqrtf(ls) + 1e-12f;
    __hip_bfloat16 l2[2] = { __float2bfloat16(lv.x / nrm),
                             __float2bfloat16(lv.y / nrm) };
    *(unsigned*)&Ln[(size_t)r * 128 + lane * 2] = *(unsigned*)l2;

    if (blockIdx.x == 0 && threadIdx.x == 0) {
        stats[0] = 0xFFFFFFFFu; stats[1] = 0u; stats[2] = 0u;
    }
}

// ----------------------------------------------- whole-tile staging ----
// Stage one 128x128 bf16 tile of A (rows rB+128) and of B (rows cB+128),
// K-slice [k0, k0+128), into LDS [chunk 16][row 128][8 elems].
// Per round: wave-uniform chunk, lane-contiguous rows (legal global_load_lds).
template<int KDIM>
__device__ __forceinline__ void stage_pair(
    const __hip_bfloat16* __restrict__ A, const __hip_bfloat16* __restrict__ Bm,
    int rB, int cB, int k0,
    short (*As)[128][8], short (*Bs)[128][8], int tid) {
    #pragma unroll
    for (int p = 0; p < 8; p++) {
        int s = p * 256 + tid;            // 16-B slot 0..2047
        int c = s >> 7, r = s & 127;
        const __hip_bfloat16* ga = A  + (size_t)(rB + r) * KDIM + k0 + c * 8;
        const __hip_bfloat16* gb = Bm + (size_t)(cB + r) * KDIM + k0 + c * 8;
        __builtin_amdgcn_global_load_lds((g_void*)ga, (l_void*)&As[c][r][0], 16, 0, 0);
        __builtin_amdgcn_global_load_lds((g_void*)gb, (l_void*)&Bs[c][r][0], 16, 0, 0);
    }
}

// 64 MFMAs over the staged K=128 tile pair (wave tile 64x64), no barriers.
__device__ __forceinline__ void mfma_tile(
    short (*As)[128][8], short (*Bs)[128][8],
    int l15, int quad, int wm, int wn, f32x4 (&acc)[4][4]) {
    #pragma unroll
    for (int kc = 0; kc < 4; kc++) {
        int ch = kc * 4 + quad;
        bf16x8 a[4], b[4];
        #pragma unroll
        for (int mi = 0; mi < 4; mi++)
            a[mi] = *(const bf16x8*)&As[ch][wm + mi * 16 + l15][0];
        #pragma unroll
        for (int ni = 0; ni < 4; ni++)
            b[ni] = *(const bf16x8*)&Bs[ch][wn + ni * 16 + l15][0];
        #pragma unroll
        for (int mi = 0; mi < 4; mi++)
            #pragma unroll
            for (int ni = 0; ni < 4; ni++)
                acc[mi][ni] = __builtin_amdgcn_mfma_f32_16x16x32_bf16(
                    a[mi], b[ni], acc[mi][ni], 0, 0, 0);
    }
}

__device__ __forceinline__ void zero_acc(f32x4 (&acc)[4][4]) {
    #pragma unroll
    for (int mi = 0; mi < 4; mi++)
        #pragma unroll
        for (int ni = 0; ni < 4; ni++) {
            f32x4 z = {0.f, 0.f, 0.f, 0.f};
            acc[mi][ni] = z;
        }
}

// ---------------------------------------------------------------- stats ----
__global__ __launch_bounds__(256, 2) void stats_kernel(
    const __hip_bfloat16* __restrict__ Ln, const __hip_bfloat16* __restrict__ Ob,
    const float* __restrict__ sq, unsigned* __restrict__ stats) {
    int bi, bj;
    tri_decode_swz(blockIdx.x, bi, bj);
    int tid = threadIdx.x, lane = tid & 63, wid = tid >> 6;
    int wm = (wid >> 1) * 64, wn = (wid & 1) * 64;
    int l15 = lane & 15, quad = lane >> 4;
    int rB = bi * TILE, cB = bj * TILE;

    __shared__ __align__(16) short As[16][128][8];   // 32 KB
    __shared__ __align__(16) short Bs[16][128][8];   // 32 KB

    float lmin = 1e30f, lmax = -1e30f, dmax = 0.f;
    f32x4 acc[4][4];

    // --- sim gram (K=128, one phase) ---
    zero_acc(acc);
    stage_pair<128>(Ln, Ln, rB, cB, 0, As, Bs, tid);
    __syncthreads();                       // drain staging
    mfma_tile(As, Bs, l15, quad, wm, wn, acc);
    #pragma unroll
    for (int mi = 0; mi < 4; mi++)
        #pragma unroll
        for (int ni = 0; ni < 4; ni++)
            #pragma unroll
            for (int r = 0; r < 4; r++) {
                float s = acc[mi][ni][r];
                lmin = fminf(lmin, s);
                lmax = fmaxf(lmax, s);
            }

    // --- out gram (K=256, two phases) ---
    zero_acc(acc);
    __syncthreads();                       // all fragment reads done
    stage_pair<256>(Ob, Ob, rB, cB, 0, As, Bs, tid);
    __syncthreads();
    mfma_tile(As, Bs, l15, quad, wm, wn, acc);
    __syncthreads();
    stage_pair<256>(Ob, Ob, rB, cB, 128, As, Bs, tid);
    __syncthreads();
    mfma_tile(As, Bs, l15, quad, wm, wn, acc);

    float sqj[4];
    #pragma unroll
    for (int ni = 0; ni < 4; ni++) sqj[ni] = sq[cB + wn + ni * 16 + l15];
    #pragma unroll
    for (int mi = 0; mi < 4; mi++) {
        f32x4 sqi = *(const f32x4*)&sq[rB + wm + mi * 16 + quad * 4];
        #pragma unroll
        for (int r = 0; r < 4; r++)
            #pragma unroll
            for (int ni = 0; ni < 4; ni++) {
                float d2 = fmaxf(sqi[r] + sqj[ni] - 2.f * acc[mi][ni][r], 0.f);
                dmax = fmaxf(dmax, d2);
            }
    }

    #pragma unroll
    for (int m = 1; m < 64; m <<= 1) {
        lmin = fminf(lmin, __shfl_xor(lmin, m));
        lmax = fmaxf(lmax, __shfl_xor(lmax, m));
        dmax = fmaxf(dmax, __shfl_xor(dmax, m));
    }
    __shared__ float red[3][4];
    if ((tid & 63) == 0) { red[0][wid] = lmin; red[1][wid] = lmax; red[2][wid] = dmax; }
    __syncthreads();
    if (tid == 0) {
        lmin = fminf(fminf(red[0][0], red[0][1]), fminf(red[0][2], red[0][3]));
        lmax = fmaxf(fmaxf(red[1][0], red[1][1]), fmaxf(red[1][2], red[1][3]));
        dmax = fmaxf(fmaxf(red[2][0], red[2][1]), fmaxf(red[2][2], red[2][3]));
        atomicMin(&stats[0], fenc(lmin));
        atomicMax(&stats[1], fenc(lmax));
        atomicMax(&stats[2], fenc(dmax));
    }
}

// ----------------------------------------------------------------- loss ----
// sim gram -> pack raw sim to f16 in 32 regs -> out gram (same LDS buffers)
// -> fused epilogue with row+col sums.
__global__ __launch_bounds__(256, 2) void loss_kernel(
    const __hip_bfloat16* __restrict__ Ln, const __hip_bfloat16* __restrict__ Ob,
    const float* __restrict__ sq, const unsigned* __restrict__ stats,
    float* __restrict__ pos_sums, float* __restrict__ neg_sums) {
    int bi, bj;
    tri_decode_swz(blockIdx.x, bi, bj);
    int tid = threadIdx.x, lane = tid & 63, wid = tid >> 6;
    int wm = (wid >> 1) * 64, wn = (wid & 1) * 64;
    int l15 = lane & 15, quad = lane >> 4;
    int rB = bi * TILE, cB = bj * TILE;

    __shared__ __align__(16) short As[16][128][8];
    __shared__ __align__(16) short Bs[16][128][8];
    __shared__ float rP[TILE][2], rN[TILE][2];
    __shared__ float cP[TILE][2], cN[TILE][2];

    f32x4 acc[4][4];

    // --- sim gram; pack raw sim into registers (f16 pairs) ---
    zero_acc(acc);
    stage_pair<128>(Ln, Ln, rB, cB, 0, As, Bs, tid);
    __syncthreads();
    mfma_tile(As, Bs, l15, quad, wm, wn, acc);
    unsigned sp[4][4][2];
    #pragma unroll
    for (int mi = 0; mi < 4; mi++)
        #pragma unroll
        for (int ni = 0; ni < 4; ni++) {
            sp[mi][ni][0] = pack2(acc[mi][ni][0], acc[mi][ni][1]);
            sp[mi][ni][1] = pack2(acc[mi][ni][2], acc[mi][ni][3]);
        }

    // --- out gram (K=256, two phases, reuses As/Bs) ---
    zero_acc(acc);
    __syncthreads();
    stage_pair<256>(Ob, Ob, rB, cB, 0, As, Bs, tid);
    __syncthreads();
    mfma_tile(As, Bs, l15, quad, wm, wn, acc);
    __syncthreads();
    stage_pair<256>(Ob, Ob, rB, cB, 128, As, Bs, tid);
    __syncthreads();
    mfma_tile(As, Bs, l15, quad, wm, wn, acc);

    float smin = fdec(stats[0]);
    float smax = fdec(stats[1]);
    float d2max = fdec(stats[2]);
    float invr = 1.f / (smax - smin);
    float invem = rsqrtf(d2max);

    float sqj[4];
    #pragma unroll
    for (int ni = 0; ni < 4; ni++) sqj[ni] = sq[cB + wn + ni * 16 + l15];
    float cpsum[4] = {0.f, 0.f, 0.f, 0.f};
    float cnsum[4] = {0.f, 0.f, 0.f, 0.f};

    #pragma unroll
    for (int mi = 0; mi < 4; mi++) {
        f32x4 sqi = *(const f32x4*)&sq[rB + wm + mi * 16 + quad * 4];
        float ps[4] = {0.f, 0.f, 0.f, 0.f};
        float ns[4] = {0.f, 0.f, 0.f, 0.f};
        #pragma unroll
        for (int ni = 0; ni < 4; ni++) {
            f16x2 s01 = *(f16x2*)&sp[mi][ni][0];
            f16x2 s23 = *(f16x2*)&sp[mi][ni][1];
            #pragma unroll
            for (int r = 0; r < 4; r++) {
                float sraw = (r < 2) ? (float)s01[r] : (float)s23[r - 2];
                float sn = (sraw - smin) * invr;
                float g = acc[mi][ni][r];
                float d2 = fmaxf(sqi[r] + sqj[ni] - 2.f * g, 0.f);
                float eud = (d2 > 0.f) ? sqrtf(d2) * invem : 0.f;
                float dist = eud + sn;
                bool pos = sn > 0.5f;   // TAU
                float pv = pos ? __expf(dist) : 0.f;
                float nv = pos ? 0.f : __expf(1.0f - dist);  // MAG = 1
                ps[r] += pv;  ns[r] += nv;
                cpsum[ni] += pv;  cnsum[ni] += nv;
            }
        }
        #pragma unroll
        for (int r = 0; r < 4; r++) {
            #pragma unroll
            for (int m = 1; m < 16; m <<= 1) {
                ps[r] += __shfl_xor(ps[r], m);
                ns[r] += __shfl_xor(ns[r], m);
            }
            if (l15 == 0) {
                int rr = wm + mi * 16 + quad * 4 + r;
                rP[rr][wid & 1] = ps[r];
                rN[rr][wid & 1] = ns[r];
            }
        }
    }
    #pragma unroll
    for (int ni = 0; ni < 4; ni++) {
        #pragma unroll
        for (int m = 16; m < 64; m <<= 1) {
            cpsum[ni] += __shfl_xor(cpsum[ni], m);
            cnsum[ni] += __shfl_xor(cnsum[ni], m);
        }
        if (quad == 0) {
            int cc = wn + ni * 16 + l15;
            cP[cc][wid >> 1] = cpsum[ni];
            cN[cc][wid >> 1] = cnsum[ni];
        }
    }
    __syncthreads();
    if (tid < TILE) {
        atomicAdd(&pos_sums[bi * TILE + tid], rP[tid][0] + rP[tid][1]);
        atomicAdd(&neg_sums[bi * TILE + tid], rN[tid][0] + rN[tid][1]);
        if (bi != bj) {
            atomicAdd(&pos_sums[bj * TILE + tid], cP[tid][0] + cP[tid][1]);
            atomicAdd(&neg_sums[bj * TILE + tid], cN[tid][0] + cN[tid][1]);
        }
    }
}

// ------------------------------------------------------------- finalize ----
__global__ __launch_bounds__(256) void finalize_kernel(
    const float* __restrict__ pos_sums, const float* __restrict__ neg_sums,
    float* __restrict__ out) {
    int t = threadIdx.x;
    float acc = 0.f;
    for (int i = t; i < B_N; i += 256) {
        float p = pos_sums[i], n = neg_sums[i];
        float pl = fmaxf(logf(p), 0.f);
        float nl = (n > 0.f) ? fmaxf(logf(n), 0.f) : 0.f;
        acc += pl + nl;
    }
    #pragma unroll
    for (int m = 1; m < 64; m <<= 1) acc += __shfl_xor(acc, m);
    __shared__ float w4[4];
    if ((t & 63) == 0) w4[t >> 6] = acc;
    __syncthreads();
    if (t == 0) out[0] = (w4[0] + w4[1] + w4[2] + w4[3]) / (float)B_N;
}

// ------------------------------------------------------------------ entry ----
extern "C" void kernel_launch(void* const* d_in, const int* in_sizes, int n_in,
                              void* d_out, int out_size, void* d_ws, size_t ws_size,
                              hipStream_t stream) {
    const float* outputs = (const float*)d_in[0];
    const float* labels  = (const float*)d_in[1];
    float* out = (float*)d_out;
    char* ws = (char*)d_ws;
    __hip_bfloat16* Ob = (__hip_bfloat16*)(ws);
    __hip_bfloat16* Ln = (__hip_bfloat16*)(ws + 4194304);
    float* sq          = (float*)(ws + 6291456);
    float* pos_sums    = (float*)(ws + 6324224);
    float* neg_sums    = (float*)(ws + 6356992);
    unsigned* stats    = (unsigned*)(ws + 6389760);

    prep_kernel<<<B_N / 4, 256, 0, stream>>>(outputs, labels, Ob, Ln, sq,
                                             pos_sums, neg_sums, stats);
    stats_kernel<<<NTRI, 256, 0, stream>>>(Ln, Ob, sq, stats);
    loss_kernel<<<NTRI, 256, 0, stream>>>(Ln, Ob, sq, stats,
                                          pos_sums, neg_sums);
    finalize_kernel<<<1, 256, 0, stream>>>(pos_sums, neg_sums, out);
}

// Round 10
// 239.819 us; speedup vs baseline: 1.1196x; 1.1196x over previous
//
#include <hip/hip_runtime.h>
#include <hip/hip_bf16.h>

// WeightedLoss round 10: COALESCED staging + XOR-swizzled LDS. Root cause of
// rounds 2-9's ~7% MfmaUtil: every staging/fragment load had a 256-512 B
// per-lane stride (lane i -> row i), touching 64 cache lines per instruction
// and using 16 B of each (~8x L2 line over-read; 400 MB staged -> ~3.2 GB of
// line traffic ~ 87 us). Now staging is a near-linear copy (lanes contiguous
// along K within each row segment); LDS octet slot op holds global octet
// op^(row&7) so ds_read_b128 fragments see only free 2-way bank aliasing.
// ws: [0] Ob bf16 8192x256 | [4 MB] Ln bf16 8192x128 | [6291456] sq f32
//     [6324224] pos_sums | [6356992] neg_sums | [6389760] stats u32[3]

#define B_N 8192
#define NT   64
#define TILE 128
#define NTRI 2080

typedef __attribute__((ext_vector_type(8))) short bf16x8;
typedef __attribute__((ext_vector_type(4))) float f32x4;
typedef __attribute__((ext_vector_type(2))) _Float16 f16x2;

typedef const __attribute__((address_space(1))) void g_void;
typedef __attribute__((address_space(3))) void l_void;

__device__ __forceinline__ unsigned fenc(float f) {
    unsigned u = __float_as_uint(f);
    return (u & 0x80000000u) ? ~u : (u | 0x80000000u);
}
__device__ __forceinline__ float fdec(unsigned k) {
    unsigned u = (k & 0x80000000u) ? (k ^ 0x80000000u) : ~k;
    return __uint_as_float(u);
}
__device__ __forceinline__ unsigned pack2(float a, float b) {
    f16x2 p; p[0] = (_Float16)a; p[1] = (_Float16)b;
    return *(unsigned*)&p;
}

// XCD-swizzled upper-tri decode.
__device__ __forceinline__ void tri_decode_swz(int b, int& bi, int& bj) {
    int t = (b & 7) * (NTRI / 8) + (b >> 3);
    int i = 0, rem = t;
    while (rem >= NT - i) { rem -= NT - i; i++; }
    bi = i; bj = i + rem;
}

// ---------------------------------------------------------------- prep ----
__global__ __launch_bounds__(256) void prep_kernel(
    const float* __restrict__ outputs, const float* __restrict__ labels,
    __hip_bfloat16* __restrict__ Ob, __hip_bfloat16* __restrict__ Ln,
    float* __restrict__ sq, float* __restrict__ pos_sums,
    float* __restrict__ neg_sums, unsigned* __restrict__ stats) {
    int w = threadIdx.x >> 6, lane = threadIdx.x & 63;
    int r = blockIdx.x * 4 + w;
    f32x4 v = ((const f32x4*)outputs)[r * 64 + lane];
    float s = v[0]*v[0] + v[1]*v[1] + v[2]*v[2] + v[3]*v[3];
    #pragma unroll
    for (int m = 1; m < 64; m <<= 1) s += __shfl_xor(s, m);
    if (lane == 0) { sq[r] = s; pos_sums[r] = 0.f; neg_sums[r] = 0.f; }
    __hip_bfloat16 o4[4];
    #pragma unroll
    for (int i = 0; i < 4; i++) o4[i] = __float2bfloat16(v[i]);
    *(uint2*)&Ob[(size_t)r * 256 + lane * 4] = *(uint2*)o4;

    float2 lv = ((const float2*)labels)[r * 64 + lane];
    float ls = lv.x * lv.x + lv.y * lv.y;
    #pragma unroll
    for (int m = 1; m < 64; m <<= 1) ls += __shfl_xor(ls, m);
    float nrm = sqrtf(ls) + 1e-12f;
    __hip_bfloat16 l2[2] = { __float2bfloat16(lv.x / nrm),
                             __float2bfloat16(lv.y / nrm) };
    *(unsigned*)&Ln[(size_t)r * 128 + lane * 2] = *(unsigned*)l2;

    if (blockIdx.x == 0 && threadIdx.x == 0) {
        stats[0] = 0xFFFFFFFFu; stats[1] = 0u; stats[2] = 0u;
    }
}

// --------------------------------------- coalesced swizzled staging ----
// Stage a 128-row x 128-K bf16 tile (rows rowBase.., K-slice k0..k0+128) into
// LDS L[128][128] (shorts). Slot s = p*256+tid: row = s>>4, octet op = s&15.
// LDS dst is linear (lane-contiguous, legal for global_load_lds); the SOURCE
// octet is op^(row&7), so physical slot op holds swizzled data and fragment
// reads (octet o at slot o^(row&7)) land 2-way-free across banks.
template<int KDIM>
__device__ __forceinline__ void stage_tile(
    const __hip_bfloat16* __restrict__ X, int rowBase, int k0,
    short* L, int tid) {
    #pragma unroll
    for (int p = 0; p < 8; p++) {
        int s = p * 256 + tid;
        int row = s >> 4, op = s & 15;
        int o = op ^ (row & 7);
        const __hip_bfloat16* g = X + (size_t)(rowBase + row) * KDIM + k0 + o * 8;
        __builtin_amdgcn_global_load_lds((g_void*)g, (l_void*)(L + (size_t)s * 8),
                                         16, 0, 0);
    }
}

// 64 MFMAs over the staged K=128 tile pair (wave tile 64x64), no barriers.
__device__ __forceinline__ void mfma_tile(
    const short* As, const short* Bs,
    int l15, int quad, int wm, int wn, f32x4 (&acc)[4][4]) {
    #pragma unroll
    for (int kc = 0; kc < 4; kc++) {
        int ch = kc * 4 + quad;
        bf16x8 a[4], b[4];
        #pragma unroll
        for (int mi = 0; mi < 4; mi++) {
            int row = wm + mi * 16 + l15;
            a[mi] = *(const bf16x8*)&As[row * 128 + ((ch ^ (row & 7)) * 8)];
        }
        #pragma unroll
        for (int ni = 0; ni < 4; ni++) {
            int row = wn + ni * 16 + l15;
            b[ni] = *(const bf16x8*)&Bs[row * 128 + ((ch ^ (row & 7)) * 8)];
        }
        #pragma unroll
        for (int mi = 0; mi < 4; mi++)
            #pragma unroll
            for (int ni = 0; ni < 4; ni++)
                acc[mi][ni] = __builtin_amdgcn_mfma_f32_16x16x32_bf16(
                    a[mi], b[ni], acc[mi][ni], 0, 0, 0);
    }
}

__device__ __forceinline__ void zero_acc(f32x4 (&acc)[4][4]) {
    #pragma unroll
    for (int mi = 0; mi < 4; mi++)
        #pragma unroll
        for (int ni = 0; ni < 4; ni++) {
            f32x4 z = {0.f, 0.f, 0.f, 0.f};
            acc[mi][ni] = z;
        }
}

// ---------------------------------------------------------------- stats ----
__global__ __launch_bounds__(256, 2) void stats_kernel(
    const __hip_bfloat16* __restrict__ Ln, const __hip_bfloat16* __restrict__ Ob,
    const float* __restrict__ sq, unsigned* __restrict__ stats) {
    int bi, bj;
    tri_decode_swz(blockIdx.x, bi, bj);
    int tid = threadIdx.x, lane = tid & 63, wid = tid >> 6;
    int wm = (wid >> 1) * 64, wn = (wid & 1) * 64;
    int l15 = lane & 15, quad = lane >> 4;
    int rB = bi * TILE, cB = bj * TILE;

    __shared__ __align__(16) short As[128 * 128];   // 32 KB
    __shared__ __align__(16) short Bs[128 * 128];   // 32 KB

    float lmin = 1e30f, lmax = -1e30f, dmax = 0.f;
    f32x4 acc[4][4];

    // --- sim gram (K=128, one phase) ---
    zero_acc(acc);
    stage_tile<128>(Ln, rB, 0, As, tid);
    stage_tile<128>(Ln, cB, 0, Bs, tid);
    __syncthreads();
    mfma_tile(As, Bs, l15, quad, wm, wn, acc);
    #pragma unroll
    for (int mi = 0; mi < 4; mi++)
        #pragma unroll
        for (int ni = 0; ni < 4; ni++)
            #pragma unroll
            for (int r = 0; r < 4; r++) {
                float s = acc[mi][ni][r];
                lmin = fminf(lmin, s);
                lmax = fmaxf(lmax, s);
            }

    // --- out gram (K=256, two phases) ---
    zero_acc(acc);
    __syncthreads();
    stage_tile<256>(Ob, rB, 0, As, tid);
    stage_tile<256>(Ob, cB, 0, Bs, tid);
    __syncthreads();
    mfma_tile(As, Bs, l15, quad, wm, wn, acc);
    __syncthreads();
    stage_tile<256>(Ob, rB, 128, As, tid);
    stage_tile<256>(Ob, cB, 128, Bs, tid);
    __syncthreads();
    mfma_tile(As, Bs, l15, quad, wm, wn, acc);

    float sqj[4];
    #pragma unroll
    for (int ni = 0; ni < 4; ni++) sqj[ni] = sq[cB + wn + ni * 16 + l15];
    #pragma unroll
    for (int mi = 0; mi < 4; mi++) {
        f32x4 sqi = *(const f32x4*)&sq[rB + wm + mi * 16 + quad * 4];
        #pragma unroll
        for (int r = 0; r < 4; r++)
            #pragma unroll
            for (int ni = 0; ni < 4; ni++) {
                float d2 = fmaxf(sqi[r] + sqj[ni] - 2.f * acc[mi][ni][r], 0.f);
                dmax = fmaxf(dmax, d2);
            }
    }

    #pragma unroll
    for (int m = 1; m < 64; m <<= 1) {
        lmin = fminf(lmin, __shfl_xor(lmin, m));
        lmax = fmaxf(lmax, __shfl_xor(lmax, m));
        dmax = fmaxf(dmax, __shfl_xor(dmax, m));
    }
    __shared__ float red[3][4];
    if ((tid & 63) == 0) { red[0][wid] = lmin; red[1][wid] = lmax; red[2][wid] = dmax; }
    __syncthreads();
    if (tid == 0) {
        lmin = fminf(fminf(red[0][0], red[0][1]), fminf(red[0][2], red[0][3]));
        lmax = fmaxf(fmaxf(red[1][0], red[1][1]), fmaxf(red[1][2], red[1][3]));
        dmax = fmaxf(fmaxf(red[2][0], red[2][1]), fmaxf(red[2][2], red[2][3]));
        atomicMin(&stats[0], fenc(lmin));
        atomicMax(&stats[1], fenc(lmax));
        atomicMax(&stats[2], fenc(dmax));
    }
}

// ----------------------------------------------------------------- loss ----
__global__ __launch_bounds__(256, 2) void loss_kernel(
    const __hip_bfloat16* __restrict__ Ln, const __hip_bfloat16* __restrict__ Ob,
    const float* __restrict__ sq, const unsigned* __restrict__ stats,
    float* __restrict__ pos_sums, float* __restrict__ neg_sums) {
    int bi, bj;
    tri_decode_swz(blockIdx.x, bi, bj);
    int tid = threadIdx.x, lane = tid & 63, wid = tid >> 6;
    int wm = (wid >> 1) * 64, wn = (wid & 1) * 64;
    int l15 = lane & 15, quad = lane >> 4;
    int rB = bi * TILE, cB = bj * TILE;

    __shared__ __align__(16) short As[128 * 128];
    __shared__ __align__(16) short Bs[128 * 128];
    __shared__ float rP[TILE][2], rN[TILE][2];
    __shared__ float cP[TILE][2], cN[TILE][2];

    f32x4 acc[4][4];

    // --- sim gram; pack raw sim to f16 pairs in 32 regs ---
    zero_acc(acc);
    stage_tile<128>(Ln, rB, 0, As, tid);
    stage_tile<128>(Ln, cB, 0, Bs, tid);
    __syncthreads();
    mfma_tile(As, Bs, l15, quad, wm, wn, acc);
    unsigned sp[4][4][2];
    #pragma unroll
    for (int mi = 0; mi < 4; mi++)
        #pragma unroll
        for (int ni = 0; ni < 4; ni++) {
            sp[mi][ni][0] = pack2(acc[mi][ni][0], acc[mi][ni][1]);
            sp[mi][ni][1] = pack2(acc[mi][ni][2], acc[mi][ni][3]);
        }

    // --- out gram (K=256, two phases) ---
    zero_acc(acc);
    __syncthreads();
    stage_tile<256>(Ob, rB, 0, As, tid);
    stage_tile<256>(Ob, cB, 0, Bs, tid);
    __syncthreads();
    mfma_tile(As, Bs, l15, quad, wm, wn, acc);
    __syncthreads();
    stage_tile<256>(Ob, rB, 128, As, tid);
    stage_tile<256>(Ob, cB, 128, Bs, tid);
    __syncthreads();
    mfma_tile(As, Bs, l15, quad, wm, wn, acc);

    float smin = fdec(stats[0]);
    float smax = fdec(stats[1]);
    float d2max = fdec(stats[2]);
    float invr = 1.f / (smax - smin);
    float invem = rsqrtf(d2max);

    float sqj[4];
    #pragma unroll
    for (int ni = 0; ni < 4; ni++) sqj[ni] = sq[cB + wn + ni * 16 + l15];
    float cpsum[4] = {0.f, 0.f, 0.f, 0.f};
    float cnsum[4] = {0.f, 0.f, 0.f, 0.f};

    #pragma unroll
    for (int mi = 0; mi < 4; mi++) {
        f32x4 sqi = *(const f32x4*)&sq[rB + wm + mi * 16 + quad * 4];
        float ps[4] = {0.f, 0.f, 0.f, 0.f};
        float ns[4] = {0.f, 0.f, 0.f, 0.f};
        #pragma unroll
        for (int ni = 0; ni < 4; ni++) {
            f16x2 s01 = *(f16x2*)&sp[mi][ni][0];
            f16x2 s23 = *(f16x2*)&sp[mi][ni][1];
            #pragma unroll
            for (int r = 0; r < 4; r++) {
                float sraw = (r < 2) ? (float)s01[r] : (float)s23[r - 2];
                float sn = (sraw - smin) * invr;
                float g = acc[mi][ni][r];
                float d2 = fmaxf(sqi[r] + sqj[ni] - 2.f * g, 0.f);
                float eud = (d2 > 0.f) ? sqrtf(d2) * invem : 0.f;
                float dist = eud + sn;
                bool pos = sn > 0.5f;   // TAU
                float pv = pos ? __expf(dist) : 0.f;
                float nv = pos ? 0.f : __expf(1.0f - dist);  // MAG = 1
                ps[r] += pv;  ns[r] += nv;
                cpsum[ni] += pv;  cnsum[ni] += nv;
            }
        }
        #pragma unroll
        for (int r = 0; r < 4; r++) {
            #pragma unroll
            for (int m = 1; m < 16; m <<= 1) {
                ps[r] += __shfl_xor(ps[r], m);
                ns[r] += __shfl_xor(ns[r], m);
            }
            if (l15 == 0) {
                int rr = wm + mi * 16 + quad * 4 + r;
                rP[rr][wid & 1] = ps[r];
                rN[rr][wid & 1] = ns[r];
            }
        }
    }
    #pragma unroll
    for (int ni = 0; ni < 4; ni++) {
        #pragma unroll
        for (int m = 16; m < 64; m <<= 1) {
            cpsum[ni] += __shfl_xor(cpsum[ni], m);
            cnsum[ni] += __shfl_xor(cnsum[ni], m);
        }
        if (quad == 0) {
            int cc = wn + ni * 16 + l15;
            cP[cc][wid >> 1] = cpsum[ni];
            cN[cc][wid >> 1] = cnsum[ni];
        }
    }
    __syncthreads();
    if (tid < TILE) {
        atomicAdd(&pos_sums[bi * TILE + tid], rP[tid][0] + rP[tid][1]);
        atomicAdd(&neg_sums[bi * TILE + tid], rN[tid][0] + rN[tid][1]);
        if (bi != bj) {
            atomicAdd(&pos_sums[bj * TILE + tid], cP[tid][0] + cP[tid][1]);
            atomicAdd(&neg_sums[bj * TILE + tid], cN[tid][0] + cN[tid][1]);
        }
    }
}

// ------------------------------------------------------------- finalize ----
__global__ __launch_bounds__(256) void finalize_kernel(
    const float* __restrict__ pos_sums, const float* __restrict__ neg_sums,
    float* __restrict__ out) {
    int t = threadIdx.x;
    float acc = 0.f;
    for (int i = t; i < B_N; i += 256) {
        float p = pos_sums[i], n = neg_sums[i];
        float pl = fmaxf(logf(p), 0.f);
        float nl = (n > 0.f) ? fmaxf(logf(n), 0.f) : 0.f;
        acc += pl + nl;
    }
    #pragma unroll
    for (int m = 1; m < 64; m <<= 1) acc += __shfl_xor(acc, m);
    __shared__ float w4[4];
    if ((t & 63) == 0) w4[t >> 6] = acc;
    __syncthreads();
    if (t == 0) out[0] = (w4[0] + w4[1] + w4[2] + w4[3]) / (float)B_N;
}

// ------------------------------------------------------------------ entry ----
extern "C" void kernel_launch(void* const* d_in, const int* in_sizes, int n_in,
                              void* d_out, int out_size, void* d_ws, size_t ws_size,
                              hipStream_t stream) {
    const float* outputs = (const float*)d_in[0];
    const float* labels  = (const float*)d_in[1];
    float* out = (float*)d_out;
    char* ws = (char*)d_ws;
    __hip_bfloat16* Ob = (__hip_bfloat16*)(ws);
    __hip_bfloat16* Ln = (__hip_bfloat16*)(ws + 4194304);
    float* sq          = (float*)(ws + 6291456);
    float* pos_sums    = (float*)(ws + 6324224);
    float* neg_sums    = (float*)(ws + 6356992);
    unsigned* stats    = (unsigned*)(ws + 6389760);

    prep_kernel<<<B_N / 4, 256, 0, stream>>>(outputs, labels, Ob, Ln, sq,
                                             pos_sums, neg_sums, stats);
    stats_kernel<<<NTRI, 256, 0, stream>>>(Ln, Ob, sq, stats);
    loss_kernel<<<NTRI, 256, 0, stream>>>(Ln, Ob, sq, stats,
                                          pos_sums, neg_sums);
    finalize_kernel<<<1, 256, 0, stream>>>(pos_sums, neg_sums, out);
}